// Round 10
// baseline (2104.060 us; speedup 1.0000x reference)
//
#include <hip/hip_runtime.h>

#define NNODES 100000
#define NEDGES 1600000
#define NG 128
#define HID 64
#define INDIM 32
#define CAT 320   // HID*(L+1)
#define ODIM 32

#define BSH 6                              // nodes per tile = 64
#define NPB 64
#define NB ((NNODES + NPB - 1) / NPB)      // 1563

#define CBSH 9                             // 512 nodes per coarse bucket
#define NCB ((NNODES + 511) / 512)         // 196
#define R1CHUNK 4096
#define NR1 ((NEDGES + R1CHUNK - 1) / R1CHUNK)   // 391
#define CAP 12288                          // radix2 LDS staging capacity

typedef unsigned short ushort_t;

__device__ __forceinline__ float bcast(float v, int lane) {
    return __uint_as_float(__builtin_amdgcn_readlane(__float_as_uint(v), lane));
}
__device__ __forceinline__ unsigned bcast_u(unsigned v, int lane) {
    return __builtin_amdgcn_readlane(v, lane);
}
__device__ __forceinline__ ushort_t f2bf(float f) {   // RTNE fp32->bf16
    unsigned u = __float_as_uint(f);
    return (ushort_t)((u + 0x7FFFu + ((u >> 16) & 1u)) >> 16);
}
__device__ __forceinline__ float bf2f(ushort_t h) {
    return __uint_as_float(((unsigned)h) << 16);
}

// ---------- 2-level radix sort of edges by dst (once per side) ----------

__global__ void radix1a_kernel(const int* __restrict__ ei, int* __restrict__ ccounts) {
    __shared__ int h[NCB];
    for (int i = threadIdx.x; i < NCB; i += blockDim.x) h[i] = 0;
    __syncthreads();
    int stride = gridDim.x * blockDim.x;
    for (int e = blockIdx.x * blockDim.x + threadIdx.x; e < NEDGES; e += stride)
        atomicAdd(&h[ei[NEDGES + e] >> CBSH], 1);
    __syncthreads();
    for (int i = threadIdx.x; i < NCB; i += blockDim.x)
        if (h[i]) atomicAdd(&ccounts[i], h[i]);
}

__global__ void cscan_kernel(const int* __restrict__ ccounts, int* __restrict__ cstart,
                             int* __restrict__ ccursor) {
    __shared__ int s[256];
    int t = threadIdx.x;
    int v = (t < NCB) ? ccounts[t] : 0;
    s[t] = v;
    for (int off = 1; off < 256; off <<= 1) {
        __syncthreads();
        int a = (t >= off) ? s[t - off] : 0;
        __syncthreads();
        s[t] += a;
    }
    __syncthreads();
    if (t < NCB) { cstart[t] = s[t] - v; ccursor[t] = s[t] - v; }
    if (t == 0) cstart[NCB] = NEDGES;
}

__global__ void __launch_bounds__(256) radix1b_kernel(
        const int* __restrict__ ei, int* __restrict__ ccursor,
        unsigned* __restrict__ packed0) {
    __shared__ int h[256], lstart[256], lpos[256], gbase[256], sc[256];
    __shared__ unsigned sdata[R1CHUNK];
    int t  = threadIdx.x;
    int e0 = blockIdx.x * R1CHUNK;
    int e1 = min(e0 + R1CHUNK, NEDGES);
    h[t] = 0; lpos[t] = 0;
    __syncthreads();
    for (int e = e0 + t; e < e1; e += blockDim.x)
        atomicAdd(&h[ei[NEDGES + e] >> CBSH], 1);
    __syncthreads();
    int v = h[t];
    sc[t] = v;
    for (int off = 1; off < 256; off <<= 1) {
        __syncthreads();
        int a = (t >= off) ? sc[t - off] : 0;
        __syncthreads();
        sc[t] += a;
    }
    __syncthreads();
    lstart[t] = sc[t] - v;
    if (t < NCB && v) gbase[t] = atomicAdd(&ccursor[t], v);
    __syncthreads();
    for (int e = e0 + t; e < e1; e += blockDim.x) {
        int dst = ei[NEDGES + e];
        int b   = dst >> CBSH;
        int p   = lstart[b] + atomicAdd(&lpos[b], 1);
        sdata[p] = (unsigned)ei[e] | ((unsigned)(dst & 511) << 20);
    }
    __syncthreads();
    int lane = t & 63, wave = t >> 6;
    for (int b = wave; b < NCB; b += 4) {
        int cnt = h[b];
        if (!cnt) continue;
        int gb = gbase[b], ls = lstart[b];
        for (int i = lane; i < cnt; i += 64) packed0[gb + i] = sdata[ls + i];
    }
}

__global__ void __launch_bounds__(256) radix2_kernel(
        const unsigned* __restrict__ packed0, const int* __restrict__ cstart,
        int* __restrict__ start, unsigned* __restrict__ packed) {
    __shared__ int cnt[512], excl[512], lpos[512], sc[256];
    __shared__ unsigned sdata[CAP];
    int b = blockIdx.x;
    int t = threadIdx.x;
    int s0 = cstart[b], s1 = cstart[b + 1];
    int n  = s1 - s0;
    for (int i = t; i < 512; i += 256) { cnt[i] = 0; lpos[i] = 0; }
    __syncthreads();
    for (int i = t; i < n; i += 256)
        atomicAdd(&cnt[(packed0[s0 + i] >> 20) & 511], 1);
    __syncthreads();
    int a  = cnt[2 * t], c2 = cnt[2 * t + 1];
    int ps = a + c2;
    sc[t] = ps;
    for (int off = 1; off < 256; off <<= 1) {
        __syncthreads();
        int x = (t >= off) ? sc[t - off] : 0;
        __syncthreads();
        sc[t] += x;
    }
    __syncthreads();
    int ex = sc[t] - ps;
    excl[2 * t] = ex; excl[2 * t + 1] = ex + a;
    __syncthreads();
    int node0 = b << CBSH;
    for (int j = t; j < 512; j += 256) {
        int node = node0 + j;
        if (node < NNODES) start[node] = s0 + excl[j];
    }
    if (b == 0 && t == 0) start[NNODES] = NEDGES;
    if (n <= CAP) {
        for (int i = t; i < n; i += 256) {
            unsigned u = packed0[s0 + i];
            int ld = (u >> 20) & 511;
            int p  = excl[ld] + atomicAdd(&lpos[ld], 1);
            sdata[p] = (u & 0xFFFFFu) | ((unsigned)(ld & 63) << 20);
        }
        __syncthreads();
        for (int i = t; i < n; i += 256) packed[s0 + i] = sdata[i];
    } else {
        for (int i = t; i < n; i += 256) {
            unsigned u = packed0[s0 + i];
            int ld = (u >> 20) & 511;
            int p  = s0 + excl[ld] + atomicAdd(&lpos[ld], 1);
            packed[p] = (u & 0xFFFFFu) | ((unsigned)(ld & 63) << 20);
        }
    }
}

// ---------- gather: 2 edges per wave-load, 16-deep asm pipeline ----------
// lanes 0-31 handle edge A (row dwords 0-31), lanes 32-63 edge B.

#define LOADV2(vv, ss) { \
    unsigned s0_ = bcast_u(u, 2*(ss))   & 0xFFFFFu; \
    unsigned s1_ = bcast_u(u, 2*(ss)+1) & 0xFFFFFu; \
    unsigned ssel_ = (lane < 32) ? s0_ : s1_; \
    const unsigned* ap_ = Xb4 + (((size_t)ssel_) << 5) + (lane & 31); \
    asm volatile("global_load_dword %0, %1, off" : "=v"(vv) : "v"(ap_)); }

#define PROCJ2(vv, ss, cnt) { \
    asm volatile("s_waitcnt vmcnt(" #cnt ")" : "+v"(vv) :: "memory"); \
    __builtin_amdgcn_sched_barrier(0); \
    unsigned d0_ = bcast_u(u, 2*(ss))   >> 20; \
    unsigned d1_ = bcast_u(u, 2*(ss)+1) >> 20; \
    unsigned ldd_ = (lane < 32) ? d0_ : d1_; \
    if (ldd_ != curv) { \
        float* tp_ = &tile[(curv << 6) + ((lane & 31) << 1)]; \
        atomicAdd(tp_, accx); atomicAdd(tp_ + 1, accy); \
        accx = 0.f; accy = 0.f; curv = ldd_; \
    } \
    accx += __uint_as_float((vv) << 16); \
    accy += __uint_as_float((vv) & 0xFFFF0000u); }

#define LOAD8_2(P, base) \
    LOADV2(P##0, (base)+0) LOADV2(P##1, (base)+1) LOADV2(P##2, (base)+2) LOADV2(P##3, (base)+3) \
    LOADV2(P##4, (base)+4) LOADV2(P##5, (base)+5) LOADV2(P##6, (base)+6) LOADV2(P##7, (base)+7)

#define PROC8_2HI(P, base) \
    PROCJ2(P##0,(base)+0,15) PROCJ2(P##1,(base)+1,14) PROCJ2(P##2,(base)+2,13) PROCJ2(P##3,(base)+3,12) \
    PROCJ2(P##4,(base)+4,11) PROCJ2(P##5,(base)+5,10) PROCJ2(P##6,(base)+6,9)  PROCJ2(P##7,(base)+7,8)

#define PROC8_2LO(P, base) \
    PROCJ2(P##0,(base)+0,7) PROCJ2(P##1,(base)+1,6) PROCJ2(P##2,(base)+2,5) PROCJ2(P##3,(base)+3,4) \
    PROCJ2(P##4,(base)+4,3) PROCJ2(P##5,(base)+5,2) PROCJ2(P##6,(base)+6,1) PROCJ2(P##7,(base)+7,0)

__global__ void __launch_bounds__(256, 8) gather_kernel(
        const ushort_t* __restrict__ Xb, const unsigned* __restrict__ packed,
        const int* __restrict__ start, float* __restrict__ AGG) {
    __shared__ float tile[(NPB + 1) * HID];   // row 64 = sentinel sink
    const unsigned* Xb4 = (const unsigned*)Xb;
    int blk = blockIdx.x;
    for (int i = threadIdx.x; i < (NPB + 1) * HID; i += blockDim.x) tile[i] = 0.f;
    __syncthreads();
    int lane   = threadIdx.x & 63;
    int wave   = threadIdx.x >> 6;
    int nw     = blockDim.x >> 6;
    int node0  = blk << BSH;
    int nvalid = min(NPB, NNODES - node0);
    int eb = start[node0];
    int ee = start[node0 + nvalid];
    int base0 = eb + wave * 64;
    if (base0 < ee) {
        unsigned u = (base0 + lane < ee) ? packed[base0 + lane] : 0u;
        unsigned curv = NPB;             // sentinel
        float accx = 0.f, accy = 0.f;
        for (int base = base0; base < ee; base += nw * 64) {
            int nv    = min(64, ee - base);
            int nbase = base + nw * 64;
            unsigned u_next = 0u;
            int have_next = nbase < ee;
            if (have_next) {             // prefetch next descriptors (oldest in vmcnt queue)
                const unsigned* dp_ = packed + nbase + lane;   // padded allocation
                asm volatile("global_load_dword %0, %1, off" : "=v"(u_next) : "v"(dp_));
            }
            if (nv == 64) {
                unsigned p0,p1,p2,p3,p4,p5,p6,p7, q0,q1,q2,q3,q4,q5,q6,q7;
                LOAD8_2(p, 0)
                LOAD8_2(q, 8)
                PROC8_2HI(p, 0)
                LOAD8_2(p, 16)
                PROC8_2HI(q, 8)
                LOAD8_2(q, 24)
                PROC8_2HI(p, 16)
                PROC8_2LO(q, 24)
            } else {                     // tail: per-edge scalar path
                float* tp_ = &tile[(curv << 6) + ((lane & 31) << 1)];
                atomicAdd(tp_, accx); atomicAdd(tp_ + 1, accy);
                accx = 0.f; accy = 0.f; curv = NPB;
                for (int k = 0; k < nv; ++k) {
                    unsigned uj = bcast_u(u, k);
                    float vv = bf2f(Xb[((size_t)(uj & 0xFFFFFu) << 6) + lane]);
                    atomicAdd(&tile[((uj >> 20) << 6) + lane], vv);
                }
            }
            if (have_next) {
                asm volatile("s_waitcnt vmcnt(0)" : "+v"(u_next) :: "memory");
                u = u_next;
            }
        }
        float* tp_ = &tile[(curv << 6) + ((lane & 31) << 1)];
        atomicAdd(tp_, accx); atomicAdd(tp_ + 1, accy);
    }
    __syncthreads();
    const float4* t4 = (const float4*)tile;
    float4* a4 = (float4*)(AGG + ((size_t)node0 << 6));
    for (int i = threadIdx.x; i < nvalid * (HID / 4); i += blockDim.x) a4[i] = t4[i];
}

// ---------- MLP: weights in LDS, register h1 broadcast, chunked pooling ----------

__global__ void mlp_kernel(const ushort_t* __restrict__ Xin, ushort_t* __restrict__ Xout,
                           const float* __restrict__ AGG,
                           float* __restrict__ XRES, float* __restrict__ G,
                           const int* __restrict__ batch,
                           const float* __restrict__ w1, const float* __restrict__ b1,
                           const float* __restrict__ w2, const float* __restrict__ b2,
                           int do_res, int stage) {
    __shared__ float sw1[HID * HID];
    __shared__ float sw2[HID * HID];
    for (int i = threadIdx.x; i < HID * HID; i += blockDim.x) {
        sw1[i] = w1[i];
        sw2[i] = w2[i];
    }
    __syncthreads();
    int lane = threadIdx.x & 63;
    int wid  = blockIdx.x * (blockDim.x >> 6) + (threadIdx.x >> 6);
    int nW   = gridDim.x * (blockDim.x >> 6);
    int chunk = (NNODES + nW - 1) / nW;
    int n0 = wid * chunk, n1 = min(n0 + chunk, NNODES);
    if (n0 >= n1) return;
    float bb1 = b1[lane], bb2 = b2[lane];
    float pool = 0.f;
    int   curg = batch[n0];
    for (int node = n0; node < n1; ++node) {
        float in   = bf2f(Xin[((size_t)node << 6) + lane]) + AGG[((size_t)node << 6) + lane];
        float acc1 = bb1;
#pragma unroll
        for (int k = 0; k < HID; ++k)
            acc1 = fmaf(bcast(in, k), sw1[k * HID + lane], acc1);
        float h1   = fmaxf(acc1, 0.f);
        float acc2 = bb2;
#pragma unroll
        for (int k = 0; k < HID; ++k)
            acc2 = fmaf(bcast(h1, k), sw2[k * HID + lane], acc2);
        if (do_res) {
            acc2 += XRES[((size_t)node << 6) + lane];
            XRES[((size_t)node << 6) + lane] = acc2;
        }
        float xn = fmaxf(acc2, 0.f);
        Xout[((size_t)node << 6) + lane] = f2bf(xn);
        int g = batch[node];
        if (g != curg) {
            atomicAdd(&G[curg * CAT + stage * HID + lane], pool);
            pool = 0.f; curg = g;
        }
        pool += xn;
    }
    atomicAdd(&G[curg * CAT + stage * HID + lane], pool);
}

// ---------- dense pieces ----------

__global__ void pre_kernel(const float* __restrict__ xin, const int* __restrict__ batch,
                           const float* __restrict__ w, const float* __restrict__ b,
                           ushort_t* __restrict__ Xb, float* __restrict__ XRES,
                           float* __restrict__ G) {
    __shared__ float sw[INDIM * HID];
    for (int i = threadIdx.x; i < INDIM * HID; i += blockDim.x) sw[i] = w[i];
    __syncthreads();
    int lane = threadIdx.x & 63;
    int wid  = blockIdx.x * (blockDim.x >> 6) + (threadIdx.x >> 6);
    int nW   = gridDim.x * (blockDim.x >> 6);
    int chunk = (NNODES + nW - 1) / nW;
    int n0 = wid * chunk, n1 = min(n0 + chunk, NNODES);
    if (n0 >= n1) return;
    float bb   = b[lane];
    float pool = 0.f;
    int   curg = batch[n0];
    for (int node = n0; node < n1; ++node) {
        float in  = (lane < INDIM) ? xin[node * INDIM + lane] : 0.f;
        float acc = bb;
#pragma unroll
        for (int k = 0; k < INDIM; ++k)
            acc = fmaf(bcast(in, k), sw[k * HID + lane], acc);
        Xb[((size_t)node << 6) + lane]   = f2bf(acc);
        XRES[((size_t)node << 6) + lane] = acc;
        int g = batch[node];
        if (g != curg) {
            atomicAdd(&G[curg * CAT + lane], pool);
            pool = 0.f; curg = g;
        }
        pool += acc;
    }
    atomicAdd(&G[curg * CAT + lane], pool);
}

__global__ void post_kernel(const float* __restrict__ GQ, const float* __restrict__ GC,
                            const float* __restrict__ w1, const float* __restrict__ b1,
                            const float* __restrict__ w2, const float* __restrict__ b2,
                            float* __restrict__ out) {
    int g    = blockIdx.x;
    int lane = threadIdx.x;
    __shared__ float h1q[HID], h1c[HID];
    float aq = b1[lane], ac = b1[lane];
    for (int k = 0; k < CAT; ++k) {
        float w = w1[k * HID + lane];
        aq = fmaf(GQ[g * CAT + k], w, aq);
        ac = fmaf(GC[g * CAT + k], w, ac);
    }
    h1q[lane] = fmaxf(aq, 0.f);
    h1c[lane] = fmaxf(ac, 0.f);
    __syncthreads();
    float s = 0.f;
    if (lane < ODIM) {
        float oq = b2[lane], oc = b2[lane];
        for (int k = 0; k < HID; ++k) {
            float w = w2[k * ODIM + lane];
            oq = fmaf(h1q[k], w, oq);
            oc = fmaf(h1c[k], w, oc);
        }
        s = fabsf(oq - oc);
    }
    for (int off = 16; off; off >>= 1) s += __shfl_down(s, off, 64);
    if (lane == 0) out[g] = s;
}

extern "C" void kernel_launch(void* const* d_in, const int* in_sizes, int n_in,
                              void* d_out, int out_size, void* d_ws, size_t ws_size,
                              hipStream_t stream) {
    const float* x_q     = (const float*)d_in[0];
    const int*   ei_q    = (const int*)d_in[1];
    const int*   batch_q = (const int*)d_in[2];
    const float* x_c     = (const float*)d_in[3];
    const int*   ei_c    = (const int*)d_in[4];
    const int*   batch_c = (const int*)d_in[5];
    const float* pre_w   = (const float*)d_in[6];
    const float* pre_b   = (const float*)d_in[7];
    const float* conv_w1 = (const float*)d_in[8];
    const float* conv_b1 = (const float*)d_in[9];
    const float* conv_w2 = (const float*)d_in[10];
    const float* conv_b2 = (const float*)d_in[11];
    const float* post_w1 = (const float*)d_in[12];
    const float* post_b1 = (const float*)d_in[13];
    const float* post_w2 = (const float*)d_in[14];
    const float* post_b2 = (const float*)d_in[15];

    float* ws   = (float*)d_ws;
    float* XRES = ws;                        // N*H fp32
    float* AGG  = XRES + NNODES * HID;       // N*H fp32
    float* GQ   = AGG + NNODES * HID;        // NG*CAT
    float* GC   = GQ + NG * CAT;             // NG*CAT
    int*   ccounts = (int*)(GC + NG * CAT);  // NCB
    int*   cstart  = ccounts + NCB;          // NCB+1
    int*   ccursor = cstart + NCB + 1;       // NCB
    int*   start   = ccursor + NCB;          // NNODES+1
    unsigned* packed0 = (unsigned*)(start + NNODES + 1);  // NEDGES+64 (padded)
    unsigned* packed  = packed0 + NEDGES + 64;            // NEDGES+64 (padded)
    ushort_t* XbfA = (ushort_t*)(packed + NEDGES + 64);   // N*H bf16
    ushort_t* XbfB = XbfA + (size_t)NNODES * HID;         // N*H bf16

    hipMemsetAsync(GQ, 0, 2 * NG * CAT * sizeof(float), stream);

    for (int side = 0; side < 2; ++side) {
        const float* xin   = side ? x_c : x_q;
        const int*   ei    = side ? ei_c : ei_q;
        const int*   batch = side ? batch_c : batch_q;
        float*       G     = side ? GC : GQ;

        hipMemsetAsync(ccounts, 0, NCB * sizeof(int), stream);
        radix1a_kernel<<<256, 256, 0, stream>>>(ei, ccounts);
        cscan_kernel<<<1, 256, 0, stream>>>(ccounts, cstart, ccursor);
        radix1b_kernel<<<NR1, 256, 0, stream>>>(ei, ccursor, packed0);
        radix2_kernel<<<NCB, 256, 0, stream>>>(packed0, cstart, start, packed);

        pre_kernel<<<1024, 256, 0, stream>>>(xin, batch, pre_w, pre_b, XbfA, XRES, G);

        ushort_t* xcur = XbfA;
        ushort_t* xnxt = XbfB;
        for (int l = 0; l < 4; ++l) {
            gather_kernel<<<NB, 256, 0, stream>>>(xcur, packed, start, AGG);
            mlp_kernel<<<1024, 256, 0, stream>>>(xcur, xnxt, AGG, XRES, G, batch,
                                                 conv_w1 + l * HID * HID, conv_b1 + l * HID,
                                                 conv_w2 + l * HID * HID, conv_b2 + l * HID,
                                                 l & 1, l + 1);
            ushort_t* t = xcur; xcur = xnxt; xnxt = t;
        }
    }

    post_kernel<<<NG, 64, 0, stream>>>(GQ, GC, post_w1, post_b1, post_w2, post_b2,
                                       (float*)d_out);
}

// Round 11
// 1731.455 us; speedup vs baseline: 1.2152x; 1.2152x over previous
//
#include <hip/hip_runtime.h>

#define NNODES 100000
#define NEDGES 1600000
#define NG 128
#define HID 64
#define INDIM 32
#define CAT 320   // HID*(L+1)
#define ODIM 32

#define BSH 6                              // nodes per tile = 64
#define NPB 64
#define NB ((NNODES + NPB - 1) / NPB)      // 1563

#define CBSH 9                             // 512 nodes per coarse bucket
#define NCB ((NNODES + 511) / 512)         // 196
#define R1CHUNK 4096
#define NR1 ((NEDGES + R1CHUNK - 1) / R1CHUNK)   // 391
#define CAP 12288                          // radix2 LDS staging capacity

typedef unsigned short ushort_t;
typedef short bf16x8 __attribute__((ext_vector_type(8)));
typedef float f32x4 __attribute__((ext_vector_type(4)));

__device__ __forceinline__ float bcast(float v, int lane) {
    return __uint_as_float(__builtin_amdgcn_readlane(__float_as_uint(v), lane));
}
__device__ __forceinline__ unsigned bcast_u(unsigned v, int lane) {
    return __builtin_amdgcn_readlane(v, lane);
}
__device__ __forceinline__ ushort_t f2bf(float f) {   // RTNE fp32->bf16
    unsigned u = __float_as_uint(f);
    return (ushort_t)((u + 0x7FFFu + ((u >> 16) & 1u)) >> 16);
}
__device__ __forceinline__ float bf2f(ushort_t h) {
    return __uint_as_float(((unsigned)h) << 16);
}

// ---------- 2-level radix sort of edges by dst (once per side) ----------

__global__ void radix1a_kernel(const int* __restrict__ ei, int* __restrict__ ccounts) {
    __shared__ int h[NCB];
    for (int i = threadIdx.x; i < NCB; i += blockDim.x) h[i] = 0;
    __syncthreads();
    int stride = gridDim.x * blockDim.x;
    for (int e = blockIdx.x * blockDim.x + threadIdx.x; e < NEDGES; e += stride)
        atomicAdd(&h[ei[NEDGES + e] >> CBSH], 1);
    __syncthreads();
    for (int i = threadIdx.x; i < NCB; i += blockDim.x)
        if (h[i]) atomicAdd(&ccounts[i], h[i]);
}

__global__ void cscan_kernel(const int* __restrict__ ccounts, int* __restrict__ cstart,
                             int* __restrict__ ccursor) {
    __shared__ int s[256];
    int t = threadIdx.x;
    int v = (t < NCB) ? ccounts[t] : 0;
    s[t] = v;
    for (int off = 1; off < 256; off <<= 1) {
        __syncthreads();
        int a = (t >= off) ? s[t - off] : 0;
        __syncthreads();
        s[t] += a;
    }
    __syncthreads();
    if (t < NCB) { cstart[t] = s[t] - v; ccursor[t] = s[t] - v; }
    if (t == 0) cstart[NCB] = NEDGES;
}

__global__ void __launch_bounds__(256) radix1b_kernel(
        const int* __restrict__ ei, int* __restrict__ ccursor,
        unsigned* __restrict__ packed0) {
    __shared__ int h[256], lstart[256], lpos[256], gbase[256], sc[256];
    __shared__ unsigned sdata[R1CHUNK];
    int t  = threadIdx.x;
    int e0 = blockIdx.x * R1CHUNK;
    int e1 = min(e0 + R1CHUNK, NEDGES);
    h[t] = 0; lpos[t] = 0;
    __syncthreads();
    for (int e = e0 + t; e < e1; e += blockDim.x)
        atomicAdd(&h[ei[NEDGES + e] >> CBSH], 1);
    __syncthreads();
    int v = h[t];
    sc[t] = v;
    for (int off = 1; off < 256; off <<= 1) {
        __syncthreads();
        int a = (t >= off) ? sc[t - off] : 0;
        __syncthreads();
        sc[t] += a;
    }
    __syncthreads();
    lstart[t] = sc[t] - v;
    if (t < NCB && v) gbase[t] = atomicAdd(&ccursor[t], v);
    __syncthreads();
    for (int e = e0 + t; e < e1; e += blockDim.x) {
        int dst = ei[NEDGES + e];
        int b   = dst >> CBSH;
        int p   = lstart[b] + atomicAdd(&lpos[b], 1);
        sdata[p] = (unsigned)ei[e] | ((unsigned)(dst & 511) << 20);
    }
    __syncthreads();
    int lane = t & 63, wave = t >> 6;
    for (int b = wave; b < NCB; b += 4) {
        int cnt = h[b];
        if (!cnt) continue;
        int gb = gbase[b], ls = lstart[b];
        for (int i = lane; i < cnt; i += 64) packed0[gb + i] = sdata[ls + i];
    }
}

__global__ void __launch_bounds__(256) radix2_kernel(
        const unsigned* __restrict__ packed0, const int* __restrict__ cstart,
        int* __restrict__ start, unsigned* __restrict__ packed) {
    __shared__ int cnt[512], excl[512], lpos[512], sc[256];
    __shared__ unsigned sdata[CAP];
    int b = blockIdx.x;
    int t = threadIdx.x;
    int s0 = cstart[b], s1 = cstart[b + 1];
    int n  = s1 - s0;
    for (int i = t; i < 512; i += 256) { cnt[i] = 0; lpos[i] = 0; }
    __syncthreads();
    for (int i = t; i < n; i += 256)
        atomicAdd(&cnt[(packed0[s0 + i] >> 20) & 511], 1);
    __syncthreads();
    int a  = cnt[2 * t], c2 = cnt[2 * t + 1];
    int ps = a + c2;
    sc[t] = ps;
    for (int off = 1; off < 256; off <<= 1) {
        __syncthreads();
        int x = (t >= off) ? sc[t - off] : 0;
        __syncthreads();
        sc[t] += x;
    }
    __syncthreads();
    int ex = sc[t] - ps;
    excl[2 * t] = ex; excl[2 * t + 1] = ex + a;
    __syncthreads();
    int node0 = b << CBSH;
    for (int j = t; j < 512; j += 256) {
        int node = node0 + j;
        if (node < NNODES) start[node] = s0 + excl[j];
    }
    if (b == 0 && t == 0) start[NNODES] = NEDGES;
    if (n <= CAP) {
        for (int i = t; i < n; i += 256) {
            unsigned u = packed0[s0 + i];
            int ld = (u >> 20) & 511;
            int p  = excl[ld] + atomicAdd(&lpos[ld], 1);
            sdata[p] = (u & 0xFFFFFu) | ((unsigned)(ld & 63) << 20);
        }
        __syncthreads();
        for (int i = t; i < n; i += 256) packed[s0 + i] = sdata[i];
    } else {
        for (int i = t; i < n; i += 256) {
            unsigned u = packed0[s0 + i];
            int ld = (u >> 20) & 511;
            int p  = s0 + excl[ld] + atomicAdd(&lpos[ld], 1);
            packed[p] = (u & 0xFFFFFu) | ((unsigned)(ld & 63) << 20);
        }
    }
}

// ---------- fused: 2-edge-packed gather + MFMA GIN-MLP ----------

#define LOADV2(vv, ss) { \
    unsigned s0_ = bcast_u(u, 2*(ss))   & 0xFFFFFu; \
    unsigned s1_ = bcast_u(u, 2*(ss)+1) & 0xFFFFFu; \
    unsigned ssel_ = (lane < 32) ? s0_ : s1_; \
    const unsigned* ap_ = Xb4 + (((size_t)ssel_) << 5) + (lane & 31); \
    asm volatile("global_load_dword %0, %1, off" : "=v"(vv) : "v"(ap_)); }

#define PROCJ2(vv, ss, cnt) { \
    asm volatile("s_waitcnt vmcnt(" #cnt ")" : "+v"(vv) :: "memory"); \
    __builtin_amdgcn_sched_barrier(0); \
    unsigned d0_ = bcast_u(u, 2*(ss))   >> 20; \
    unsigned d1_ = bcast_u(u, 2*(ss)+1) >> 20; \
    unsigned ldd_ = (lane < 32) ? d0_ : d1_; \
    if (ldd_ != curv) { \
        float* tp_ = &tile[(curv << 6) + ((lane & 31) << 1)]; \
        atomicAdd(tp_, accx); atomicAdd(tp_ + 1, accy); \
        accx = 0.f; accy = 0.f; curv = ldd_; \
    } \
    accx += __uint_as_float((vv) << 16); \
    accy += __uint_as_float((vv) & 0xFFFF0000u); }

#define LOAD8_2(P, base) \
    LOADV2(P##0, (base)+0) LOADV2(P##1, (base)+1) LOADV2(P##2, (base)+2) LOADV2(P##3, (base)+3) \
    LOADV2(P##4, (base)+4) LOADV2(P##5, (base)+5) LOADV2(P##6, (base)+6) LOADV2(P##7, (base)+7)

#define PROC8_2HI(P, base) \
    PROCJ2(P##0,(base)+0,15) PROCJ2(P##1,(base)+1,14) PROCJ2(P##2,(base)+2,13) PROCJ2(P##3,(base)+3,12) \
    PROCJ2(P##4,(base)+4,11) PROCJ2(P##5,(base)+5,10) PROCJ2(P##6,(base)+6,9)  PROCJ2(P##7,(base)+7,8)

#define PROC8_2LO(P, base) \
    PROCJ2(P##0,(base)+0,7) PROCJ2(P##1,(base)+1,6) PROCJ2(P##2,(base)+2,5) PROCJ2(P##3,(base)+3,4) \
    PROCJ2(P##4,(base)+4,3) PROCJ2(P##5,(base)+5,2) PROCJ2(P##6,(base)+6,1) PROCJ2(P##7,(base)+7,0)

#define CVT8(av, lo, hi) { \
    av[0] = (short)f2bf((lo).x); av[1] = (short)f2bf((lo).y); \
    av[2] = (short)f2bf((lo).z); av[3] = (short)f2bf((lo).w); \
    av[4] = (short)f2bf((hi).x); av[5] = (short)f2bf((hi).y); \
    av[6] = (short)f2bf((hi).z); av[7] = (short)f2bf((hi).w); }

__global__ void __launch_bounds__(256) fused_kernel(
        const ushort_t* __restrict__ Xb, ushort_t* __restrict__ Xb_out,
        float* __restrict__ XRES, float* __restrict__ G,
        const int* __restrict__ batch,
        const unsigned* __restrict__ packed, const int* __restrict__ start,
        const float* __restrict__ w1, const float* __restrict__ bs1,
        const float* __restrict__ w2, const float* __restrict__ bs2,
        int do_res, int stage) {
    __shared__ float    tile[(NPB + 1) * HID];   // x + agg (f32); row 64 = sentinel
    __shared__ ushort_t swt[HID * HID];          // W^T bf16 (staged twice)
    __shared__ ushort_t hl[NPB * HID];           // h1 bf16
    const unsigned* Xb4 = (const unsigned*)Xb;
    int blk    = blockIdx.x;
    int lane   = threadIdx.x & 63;
    int wave   = threadIdx.x >> 6;
    int nw     = blockDim.x >> 6;
    int node0  = blk << BSH;
    int nvalid = min(NPB, NNODES - node0);
    // init tile = x (bf16->f32); invalid + sentinel rows = 0
    for (int i = threadIdx.x; i < (NPB + 1) * HID; i += blockDim.x) {
        int row = i >> 6;
        tile[i] = (row < nvalid) ? bf2f(Xb[((size_t)node0 << 6) + i]) : 0.f;
    }
    // stage W1^T as bf16: swt[n*64+k] = w1[k*64+n]
    for (int idx = threadIdx.x; idx < HID * HID; idx += blockDim.x)
        swt[(idx & 63) * HID + (idx >> 6)] = f2bf(w1[idx]);
    __syncthreads();
    // ---- gather phase ----
    int eb = start[node0];
    int ee = start[node0 + nvalid];
    int base0 = eb + wave * 64;
    if (base0 < ee) {
        unsigned u = (base0 + lane < ee) ? packed[base0 + lane] : 0u;
        unsigned curv = NPB;             // sentinel row
        float accx = 0.f, accy = 0.f;
        for (int base = base0; base < ee; base += nw * 64) {
            int nv    = min(64, ee - base);
            int nbase = base + nw * 64;
            unsigned u_next = 0u;
            int have_next = nbase < ee;
            if (have_next) {
                const unsigned* dp_ = packed + nbase + lane;
                asm volatile("global_load_dword %0, %1, off" : "=v"(u_next) : "v"(dp_));
            }
            if (nv == 64) {
                unsigned p0,p1,p2,p3,p4,p5,p6,p7, q0,q1,q2,q3,q4,q5,q6,q7;
                LOAD8_2(p, 0)
                LOAD8_2(q, 8)
                PROC8_2HI(p, 0)
                LOAD8_2(p, 16)
                PROC8_2HI(q, 8)
                LOAD8_2(q, 24)
                PROC8_2HI(p, 16)
                PROC8_2LO(q, 24)
            } else {
                float* tp_ = &tile[(curv << 6) + ((lane & 31) << 1)];
                atomicAdd(tp_, accx); atomicAdd(tp_ + 1, accy);
                accx = 0.f; accy = 0.f; curv = NPB;
                for (int k = 0; k < nv; ++k) {
                    unsigned uj = bcast_u(u, k);
                    float vv = bf2f(Xb[((size_t)(uj & 0xFFFFFu) << 6) + lane]);
                    atomicAdd(&tile[((uj >> 20) << 6) + lane], vv);
                }
            }
            if (have_next) {
                asm volatile("s_waitcnt vmcnt(0)" : "+v"(u_next) :: "memory");
                u = u_next;
            }
        }
        float* tp_ = &tile[(curv << 6) + ((lane & 31) << 1)];
        atomicAdd(tp_, accx); atomicAdd(tp_ + 1, accy);
    }
    __syncthreads();
    // ---- GEMM1 (MFMA): h1 = relu((x+agg) @ W1 + b1), wave owns 16-row stripe ----
    int m  = lane & 15;
    int kg = lane >> 4;
    int r0 = wave << 4;
    {
        const float* ar = &tile[((r0 + m) << 6) + (kg << 3)];
        float4 lo0 = *(const float4*)(ar);
        float4 hi0 = *(const float4*)(ar + 4);
        float4 lo1 = *(const float4*)(ar + 32);
        float4 hi1 = *(const float4*)(ar + 36);
        bf16x8 a0, a1;
        CVT8(a0, lo0, hi0)
        CVT8(a1, lo1, hi1)
        f32x4 acc[4];
#pragma unroll
        for (int t = 0; t < 4; ++t) {
            acc[t] = 0.f;
            const ushort_t* bp = &swt[((16 * t + m) << 6) + (kg << 3)];
            bf16x8 b0 = *(const bf16x8*)bp;
            bf16x8 b1 = *(const bf16x8*)(bp + 32);
            acc[t] = __builtin_amdgcn_mfma_f32_16x16x32_bf16(a0, b0, acc[t], 0, 0, 0);
            acc[t] = __builtin_amdgcn_mfma_f32_16x16x32_bf16(a1, b1, acc[t], 0, 0, 0);
        }
#pragma unroll
        for (int t = 0; t < 4; ++t) {
            float bv = bs1[16 * t + m];
#pragma unroll
            for (int reg = 0; reg < 4; ++reg) {
                int lr = r0 + (kg << 2) + reg;
                hl[(lr << 6) + 16 * t + m] = f2bf(fmaxf(acc[t][reg] + bv, 0.f));
            }
        }
    }
    __syncthreads();
    for (int idx = threadIdx.x; idx < HID * HID; idx += blockDim.x)
        swt[(idx & 63) * HID + (idx >> 6)] = f2bf(w2[idx]);
    __syncthreads();
    // ---- GEMM2 (MFMA): out = h1 @ W2 + b2 [+res]; relu; pool ----
    {
        const ushort_t* hr = &hl[((r0 + m) << 6) + (kg << 3)];
        bf16x8 a0 = *(const bf16x8*)hr;
        bf16x8 a1 = *(const bf16x8*)(hr + 32);
        f32x4 acc[4];
#pragma unroll
        for (int t = 0; t < 4; ++t) {
            acc[t] = 0.f;
            const ushort_t* bp = &swt[((16 * t + m) << 6) + (kg << 3)];
            bf16x8 b0 = *(const bf16x8*)bp;
            bf16x8 b1 = *(const bf16x8*)(bp + 32);
            acc[t] = __builtin_amdgcn_mfma_f32_16x16x32_bf16(a0, b0, acc[t], 0, 0, 0);
            acc[t] = __builtin_amdgcn_mfma_f32_16x16x32_bf16(a1, b1, acc[t], 0, 0, 0);
        }
        float bv2[4];
#pragma unroll
        for (int t = 0; t < 4; ++t) bv2[t] = bs2[16 * t + m];
        int baserow = node0 + r0 + (kg << 2);
        float pool[4] = {0.f, 0.f, 0.f, 0.f};
        int gcur = -1;
#pragma unroll
        for (int reg = 0; reg < 4; ++reg) {
            int node = baserow + reg;
            if (node >= NNODES) break;
            int g = batch[node];
            if (g != gcur) {
                if (gcur >= 0) {
#pragma unroll
                    for (int t = 0; t < 4; ++t) {
                        atomicAdd(&G[gcur * CAT + stage * HID + 16 * t + m], pool[t]);
                        pool[t] = 0.f;
                    }
                }
                gcur = g;
            }
#pragma unroll
            for (int t = 0; t < 4; ++t) {
                int c = 16 * t + m;
                float v = acc[t][reg] + bv2[t];
                if (do_res) {
                    v += XRES[((size_t)node << 6) + c];
                    XRES[((size_t)node << 6) + c] = v;
                }
                float xn = fmaxf(v, 0.f);
                Xb_out[((size_t)node << 6) + c] = f2bf(xn);
                pool[t] += xn;
            }
        }
        if (gcur >= 0) {
#pragma unroll
            for (int t = 0; t < 4; ++t)
                atomicAdd(&G[gcur * CAT + stage * HID + 16 * t + m], pool[t]);
        }
    }
}

// ---------- dense pieces ----------

__global__ void pre_kernel(const float* __restrict__ xin, const int* __restrict__ batch,
                           const float* __restrict__ w, const float* __restrict__ b,
                           ushort_t* __restrict__ Xb, float* __restrict__ XRES,
                           float* __restrict__ G) {
    __shared__ float sw[INDIM * HID];
    for (int i = threadIdx.x; i < INDIM * HID; i += blockDim.x) sw[i] = w[i];
    __syncthreads();
    int lane = threadIdx.x & 63;
    int wid  = blockIdx.x * (blockDim.x >> 6) + (threadIdx.x >> 6);
    int nW   = gridDim.x * (blockDim.x >> 6);
    int chunk = (NNODES + nW - 1) / nW;
    int n0 = wid * chunk, n1 = min(n0 + chunk, NNODES);
    if (n0 >= n1) return;
    float bb   = b[lane];
    float pool = 0.f;
    int   curg = batch[n0];
    for (int node = n0; node < n1; ++node) {
        float in  = (lane < INDIM) ? xin[node * INDIM + lane] : 0.f;
        float acc = bb;
#pragma unroll
        for (int k = 0; k < INDIM; ++k)
            acc = fmaf(bcast(in, k), sw[k * HID + lane], acc);
        Xb[((size_t)node << 6) + lane]   = f2bf(acc);
        XRES[((size_t)node << 6) + lane] = acc;
        int g = batch[node];
        if (g != curg) {
            atomicAdd(&G[curg * CAT + lane], pool);
            pool = 0.f; curg = g;
        }
        pool += acc;
    }
    atomicAdd(&G[curg * CAT + lane], pool);
}

__global__ void post_kernel(const float* __restrict__ GQ, const float* __restrict__ GC,
                            const float* __restrict__ w1, const float* __restrict__ b1,
                            const float* __restrict__ w2, const float* __restrict__ b2,
                            float* __restrict__ out) {
    int g    = blockIdx.x;
    int lane = threadIdx.x;
    __shared__ float h1q[HID], h1c[HID];
    float aq = b1[lane], ac = b1[lane];
    for (int k = 0; k < CAT; ++k) {
        float w = w1[k * HID + lane];
        aq = fmaf(GQ[g * CAT + k], w, aq);
        ac = fmaf(GC[g * CAT + k], w, ac);
    }
    h1q[lane] = fmaxf(aq, 0.f);
    h1c[lane] = fmaxf(ac, 0.f);
    __syncthreads();
    float s = 0.f;
    if (lane < ODIM) {
        float oq = b2[lane], oc = b2[lane];
        for (int k = 0; k < HID; ++k) {
            float w = w2[k * ODIM + lane];
            oq = fmaf(h1q[k], w, oq);
            oc = fmaf(h1c[k], w, oc);
        }
        s = fabsf(oq - oc);
    }
    for (int off = 16; off; off >>= 1) s += __shfl_down(s, off, 64);
    if (lane == 0) out[g] = s;
}

extern "C" void kernel_launch(void* const* d_in, const int* in_sizes, int n_in,
                              void* d_out, int out_size, void* d_ws, size_t ws_size,
                              hipStream_t stream) {
    const float* x_q     = (const float*)d_in[0];
    const int*   ei_q    = (const int*)d_in[1];
    const int*   batch_q = (const int*)d_in[2];
    const float* x_c     = (const float*)d_in[3];
    const int*   ei_c    = (const int*)d_in[4];
    const int*   batch_c = (const int*)d_in[5];
    const float* pre_w   = (const float*)d_in[6];
    const float* pre_b   = (const float*)d_in[7];
    const float* conv_w1 = (const float*)d_in[8];
    const float* conv_b1 = (const float*)d_in[9];
    const float* conv_w2 = (const float*)d_in[10];
    const float* conv_b2 = (const float*)d_in[11];
    const float* post_w1 = (const float*)d_in[12];
    const float* post_b1 = (const float*)d_in[13];
    const float* post_w2 = (const float*)d_in[14];
    const float* post_b2 = (const float*)d_in[15];

    float* ws   = (float*)d_ws;
    float* XRES = ws;                        // N*H fp32
    float* GQ   = XRES + NNODES * HID;       // NG*CAT
    float* GC   = GQ + NG * CAT;             // NG*CAT
    int*   ccounts = (int*)(GC + NG * CAT);  // NCB
    int*   cstart  = ccounts + NCB;          // NCB+1
    int*   ccursor = cstart + NCB + 1;       // NCB
    int*   start   = ccursor + NCB;          // NNODES+1
    unsigned* packed0 = (unsigned*)(start + NNODES + 1);  // NEDGES+64 (padded)
    unsigned* packed  = packed0 + NEDGES + 64;            // NEDGES+64 (padded)
    ushort_t* XbfA = (ushort_t*)(packed + NEDGES + 64);   // N*H bf16
    ushort_t* XbfB = XbfA + (size_t)NNODES * HID;         // N*H bf16

    hipMemsetAsync(GQ, 0, 2 * NG * CAT * sizeof(float), stream);

    for (int side = 0; side < 2; ++side) {
        const float* xin   = side ? x_c : x_q;
        const int*   ei    = side ? ei_c : ei_q;
        const int*   batch = side ? batch_c : batch_q;
        float*       G     = side ? GC : GQ;

        hipMemsetAsync(ccounts, 0, NCB * sizeof(int), stream);
        radix1a_kernel<<<256, 256, 0, stream>>>(ei, ccounts);
        cscan_kernel<<<1, 256, 0, stream>>>(ccounts, cstart, ccursor);
        radix1b_kernel<<<NR1, 256, 0, stream>>>(ei, ccursor, packed0);
        radix2_kernel<<<NCB, 256, 0, stream>>>(packed0, cstart, start, packed);

        pre_kernel<<<1024, 256, 0, stream>>>(xin, batch, pre_w, pre_b, XbfA, XRES, G);

        ushort_t* xcur = XbfA;
        ushort_t* xnxt = XbfB;
        for (int l = 0; l < 4; ++l) {
            fused_kernel<<<NB, 256, 0, stream>>>(xcur, xnxt, XRES, G, batch, packed, start,
                                                 conv_w1 + l * HID * HID, conv_b1 + l * HID,
                                                 conv_w2 + l * HID * HID, conv_b2 + l * HID,
                                                 l & 1, l + 1);
            ushort_t* t = xcur; xcur = xnxt; xnxt = t;
        }
    }

    post_kernel<<<NG, 64, 0, stream>>>(GQ, GC, post_w1, post_b1, post_w2, post_b2,
                                       (float*)d_out);
}

// Round 12
// 1523.922 us; speedup vs baseline: 1.3807x; 1.1362x over previous
//
#include <hip/hip_runtime.h>

#define NNODES 100000
#define NEDGES 1600000
#define NG 128
#define HID 64
#define INDIM 32
#define CAT 320   // HID*(L+1)
#define ODIM 32

#define BSH 6                              // nodes per tile = 64
#define NPB 64
#define NB ((NNODES + NPB - 1) / NPB)      // 1563

#define CBSH 9                             // 512 nodes per coarse bucket
#define NCB ((NNODES + 511) / 512)         // 196
#define R1CHUNK 4096
#define NR1 ((NEDGES + R1CHUNK - 1) / R1CHUNK)   // 391
#define CAP 12288                          // radix2 LDS staging capacity

typedef unsigned short ushort_t;
typedef short bf16x8 __attribute__((ext_vector_type(8)));
typedef float f32x4 __attribute__((ext_vector_type(4)));

__device__ __forceinline__ float bcast(float v, int lane) {
    return __uint_as_float(__builtin_amdgcn_readlane(__float_as_uint(v), lane));
}
__device__ __forceinline__ unsigned bcast_u(unsigned v, int lane) {
    return __builtin_amdgcn_readlane(v, lane);
}
__device__ __forceinline__ ushort_t f2bf(float f) {   // RTNE fp32->bf16
    unsigned u = __float_as_uint(f);
    return (ushort_t)((u + 0x7FFFu + ((u >> 16) & 1u)) >> 16);
}
__device__ __forceinline__ float bf2f(ushort_t h) {
    return __uint_as_float(((unsigned)h) << 16);
}

// ---------- 2-level radix sort of edges by dst (once per side) ----------

__global__ void radix1a_kernel(const int* __restrict__ ei, int* __restrict__ ccounts) {
    __shared__ int h[NCB];
    for (int i = threadIdx.x; i < NCB; i += blockDim.x) h[i] = 0;
    __syncthreads();
    int stride = gridDim.x * blockDim.x;
    for (int e = blockIdx.x * blockDim.x + threadIdx.x; e < NEDGES; e += stride)
        atomicAdd(&h[ei[NEDGES + e] >> CBSH], 1);
    __syncthreads();
    for (int i = threadIdx.x; i < NCB; i += blockDim.x)
        if (h[i]) atomicAdd(&ccounts[i], h[i]);
}

__global__ void cscan_kernel(const int* __restrict__ ccounts, int* __restrict__ cstart,
                             int* __restrict__ ccursor) {
    __shared__ int s[256];
    int t = threadIdx.x;
    int v = (t < NCB) ? ccounts[t] : 0;
    s[t] = v;
    for (int off = 1; off < 256; off <<= 1) {
        __syncthreads();
        int a = (t >= off) ? s[t - off] : 0;
        __syncthreads();
        s[t] += a;
    }
    __syncthreads();
    if (t < NCB) { cstart[t] = s[t] - v; ccursor[t] = s[t] - v; }
    if (t == 0) cstart[NCB] = NEDGES;
}

__global__ void __launch_bounds__(256) radix1b_kernel(
        const int* __restrict__ ei, int* __restrict__ ccursor,
        unsigned* __restrict__ packed0) {
    __shared__ int h[256], lstart[256], lpos[256], gbase[256], sc[256];
    __shared__ unsigned sdata[R1CHUNK];
    int t  = threadIdx.x;
    int e0 = blockIdx.x * R1CHUNK;
    int e1 = min(e0 + R1CHUNK, NEDGES);
    h[t] = 0; lpos[t] = 0;
    __syncthreads();
    for (int e = e0 + t; e < e1; e += blockDim.x)
        atomicAdd(&h[ei[NEDGES + e] >> CBSH], 1);
    __syncthreads();
    int v = h[t];
    sc[t] = v;
    for (int off = 1; off < 256; off <<= 1) {
        __syncthreads();
        int a = (t >= off) ? sc[t - off] : 0;
        __syncthreads();
        sc[t] += a;
    }
    __syncthreads();
    lstart[t] = sc[t] - v;
    if (t < NCB && v) gbase[t] = atomicAdd(&ccursor[t], v);
    __syncthreads();
    for (int e = e0 + t; e < e1; e += blockDim.x) {
        int dst = ei[NEDGES + e];
        int b   = dst >> CBSH;
        int p   = lstart[b] + atomicAdd(&lpos[b], 1);
        sdata[p] = (unsigned)ei[e] | ((unsigned)(dst & 511) << 20);
    }
    __syncthreads();
    int lane = t & 63, wave = t >> 6;
    for (int b = wave; b < NCB; b += 4) {
        int cnt = h[b];
        if (!cnt) continue;
        int gb = gbase[b], ls = lstart[b];
        for (int i = lane; i < cnt; i += 64) packed0[gb + i] = sdata[ls + i];
    }
}

__global__ void __launch_bounds__(256) radix2_kernel(
        const unsigned* __restrict__ packed0, const int* __restrict__ cstart,
        int* __restrict__ start, unsigned* __restrict__ packed) {
    __shared__ int cnt[512], excl[512], lpos[512], sc[256];
    __shared__ unsigned sdata[CAP];
    int b = blockIdx.x;
    int t = threadIdx.x;
    int s0 = cstart[b], s1 = cstart[b + 1];
    int n  = s1 - s0;
    for (int i = t; i < 512; i += 256) { cnt[i] = 0; lpos[i] = 0; }
    __syncthreads();
    for (int i = t; i < n; i += 256)
        atomicAdd(&cnt[(packed0[s0 + i] >> 20) & 511], 1);
    __syncthreads();
    int a  = cnt[2 * t], c2 = cnt[2 * t + 1];
    int ps = a + c2;
    sc[t] = ps;
    for (int off = 1; off < 256; off <<= 1) {
        __syncthreads();
        int x = (t >= off) ? sc[t - off] : 0;
        __syncthreads();
        sc[t] += x;
    }
    __syncthreads();
    int ex = sc[t] - ps;
    excl[2 * t] = ex; excl[2 * t + 1] = ex + a;
    __syncthreads();
    int node0 = b << CBSH;
    for (int j = t; j < 512; j += 256) {
        int node = node0 + j;
        if (node < NNODES) start[node] = s0 + excl[j];
    }
    if (b == 0 && t == 0) start[NNODES] = NEDGES;
    if (n <= CAP) {
        for (int i = t; i < n; i += 256) {
            unsigned u = packed0[s0 + i];
            int ld = (u >> 20) & 511;
            int p  = excl[ld] + atomicAdd(&lpos[ld], 1);
            sdata[p] = (u & 0xFFFFFu) | ((unsigned)(ld & 63) << 20);
        }
        __syncthreads();
        for (int i = t; i < n; i += 256) packed[s0 + i] = sdata[i];
    } else {
        for (int i = t; i < n; i += 256) {
            unsigned u = packed0[s0 + i];
            int ld = (u >> 20) & 511;
            int p  = s0 + excl[ld] + atomicAdd(&lpos[ld], 1);
            packed[p] = (u & 0xFFFFFu) | ((unsigned)(ld & 63) << 20);
        }
    }
}

// ---------- weight prep: transposed bf16 fragments in global (once per launch) ----------
// wtbuf[mat][c*64+k] = bf16(W[k][c]);  mat 0..3 = W1 of layer, 4..7 = W2 of layer.

__global__ void wtprep_kernel(const float* __restrict__ cw1, const float* __restrict__ cw2,
                              ushort_t* __restrict__ wtbuf) {
    int mat = blockIdx.x;
    const float* src = (mat < 4) ? cw1 + mat * HID * HID : cw2 + (mat - 4) * HID * HID;
    ushort_t* dst = wtbuf + mat * HID * HID;
    for (int idx = threadIdx.x; idx < HID * HID; idx += blockDim.x) {
        int c = idx >> 6, k = idx & 63;
        dst[idx] = f2bf(src[k * HID + c]);
    }
}

// ---------- fused: 2-edge-packed gather + MFMA GIN-MLP (swizzled LDS) ----------
// tile swizzle: 16B-block index ^= (row & 7)   [row stride 256 B f32]
// hl   swizzle: 16B-block index ^= (row & 7)   [row stride 128 B bf16]

#define LOADV2(vv, ss) { \
    unsigned s0_ = bcast_u(u, 2*(ss))   & 0xFFFFFu; \
    unsigned s1_ = bcast_u(u, 2*(ss)+1) & 0xFFFFFu; \
    unsigned ssel_ = (lane < 32) ? s0_ : s1_; \
    const unsigned* ap_ = Xb4 + (((size_t)ssel_) << 5) + (lane & 31); \
    asm volatile("global_load_dword %0, %1, off" : "=v"(vv) : "v"(ap_)); }

#define TILE_PAIR(row_, hb_) \
    (&tile[((row_) << 6) + (((((hb_) >> 1) ^ ((row_) & 7))) << 2) + (((hb_) & 1) << 1)])

#define PROCJ2(vv, ss, cnt) { \
    asm volatile("s_waitcnt vmcnt(" #cnt ")" : "+v"(vv) :: "memory"); \
    __builtin_amdgcn_sched_barrier(0); \
    unsigned d0_ = bcast_u(u, 2*(ss))   >> 20; \
    unsigned d1_ = bcast_u(u, 2*(ss)+1) >> 20; \
    unsigned ldd_ = (lane < 32) ? d0_ : d1_; \
    if (ldd_ != curv) { \
        float* tp_ = TILE_PAIR(curv, (lane & 31)); \
        atomicAdd(tp_, accx); atomicAdd(tp_ + 1, accy); \
        accx = 0.f; accy = 0.f; curv = ldd_; \
    } \
    accx += __uint_as_float((vv) << 16); \
    accy += __uint_as_float((vv) & 0xFFFF0000u); }

#define LOAD8_2(P, base) \
    LOADV2(P##0, (base)+0) LOADV2(P##1, (base)+1) LOADV2(P##2, (base)+2) LOADV2(P##3, (base)+3) \
    LOADV2(P##4, (base)+4) LOADV2(P##5, (base)+5) LOADV2(P##6, (base)+6) LOADV2(P##7, (base)+7)

#define PROC8_2HI(P, base) \
    PROCJ2(P##0,(base)+0,15) PROCJ2(P##1,(base)+1,14) PROCJ2(P##2,(base)+2,13) PROCJ2(P##3,(base)+3,12) \
    PROCJ2(P##4,(base)+4,11) PROCJ2(P##5,(base)+5,10) PROCJ2(P##6,(base)+6,9)  PROCJ2(P##7,(base)+7,8)

#define PROC8_2LO(P, base) \
    PROCJ2(P##0,(base)+0,7) PROCJ2(P##1,(base)+1,6) PROCJ2(P##2,(base)+2,5) PROCJ2(P##3,(base)+3,4) \
    PROCJ2(P##4,(base)+4,3) PROCJ2(P##5,(base)+5,2) PROCJ2(P##6,(base)+6,1) PROCJ2(P##7,(base)+7,0)

#define CVT8(av, lo, hi) { \
    av[0] = (short)f2bf((lo).x); av[1] = (short)f2bf((lo).y); \
    av[2] = (short)f2bf((lo).z); av[3] = (short)f2bf((lo).w); \
    av[4] = (short)f2bf((hi).x); av[5] = (short)f2bf((hi).y); \
    av[6] = (short)f2bf((hi).z); av[7] = (short)f2bf((hi).w); }

__global__ void __launch_bounds__(256, 6) fused_kernel(
        const ushort_t* __restrict__ Xb, ushort_t* __restrict__ Xb_out,
        float* __restrict__ XRES, float* __restrict__ G,
        const int* __restrict__ batch,
        const unsigned* __restrict__ packed, const int* __restrict__ start,
        const ushort_t* __restrict__ wt1, const float* __restrict__ bs1,
        const ushort_t* __restrict__ wt2, const float* __restrict__ bs2,
        int do_res, int stage) {
    __shared__ float    tile[(NPB + 1) * HID];   // x + agg (f32), swizzled; row 64 = sentinel
    __shared__ ushort_t hl[NPB * HID];           // h1 bf16, swizzled
    const unsigned* Xb4 = (const unsigned*)Xb;
    int blk    = blockIdx.x;
    int lane   = threadIdx.x & 63;
    int wave   = threadIdx.x >> 6;
    int nw     = blockDim.x >> 6;
    int node0  = blk << BSH;
    int nvalid = min(NPB, NNODES - node0);
    // init tile = x (bf16->f32), swizzled; invalid + sentinel rows = 0
    for (int i = threadIdx.x; i < (NPB + 1) * HID; i += blockDim.x) {
        int row = i >> 6, col = i & 63;
        int sidx = (row << 6) + ((((col >> 2) ^ (row & 7)) << 2) | (col & 3));
        tile[sidx] = (row < nvalid) ? bf2f(Xb[((size_t)node0 << 6) + i]) : 0.f;
    }
    __syncthreads();
    // ---- gather phase ----
    int eb = start[node0];
    int ee = start[node0 + nvalid];
    int base0 = eb + wave * 64;
    if (base0 < ee) {
        unsigned u = (base0 + lane < ee) ? packed[base0 + lane] : 0u;
        unsigned curv = NPB;             // sentinel row
        float accx = 0.f, accy = 0.f;
        for (int base = base0; base < ee; base += nw * 64) {
            int nv    = min(64, ee - base);
            int nbase = base + nw * 64;
            unsigned u_next = 0u;
            int have_next = nbase < ee;
            if (have_next) {
                const unsigned* dp_ = packed + nbase + lane;
                asm volatile("global_load_dword %0, %1, off" : "=v"(u_next) : "v"(dp_));
            }
            if (nv == 64) {
                unsigned p0,p1,p2,p3,p4,p5,p6,p7, q0,q1,q2,q3,q4,q5,q6,q7;
                LOAD8_2(p, 0)
                LOAD8_2(q, 8)
                PROC8_2HI(p, 0)
                LOAD8_2(p, 16)
                PROC8_2HI(q, 8)
                LOAD8_2(q, 24)
                PROC8_2HI(p, 16)
                PROC8_2LO(q, 24)
            } else {
                float* tp_ = TILE_PAIR(curv, (lane & 31));
                atomicAdd(tp_, accx); atomicAdd(tp_ + 1, accy);
                accx = 0.f; accy = 0.f; curv = NPB;
                for (int k = 0; k < nv; ++k) {
                    unsigned uj = bcast_u(u, k);
                    float vv = bf2f(Xb[((size_t)(uj & 0xFFFFFu) << 6) + lane]);
                    int rw = (int)(uj >> 20);
                    atomicAdd(&tile[(rw << 6) + (((lane >> 2) ^ (rw & 7)) << 2) + (lane & 3)], vv);
                }
            }
            if (have_next) {
                asm volatile("s_waitcnt vmcnt(0)" : "+v"(u_next) :: "memory");
                u = u_next;
            }
        }
        float* tp_ = TILE_PAIR(curv, (lane & 31));
        atomicAdd(tp_, accx); atomicAdd(tp_ + 1, accy);
    }
    __syncthreads();
    // ---- GEMM1 (MFMA): h1 = relu((x+agg) @ W1 + b1), wave owns 16-row stripe ----
    int m  = lane & 15;
    int kg = lane >> 4;
    int r0 = wave << 4;
    int r7 = m & 7;                      // (r0+m)&7 == m&7 (r0 multiple of 16)
    {
        const float* ar = &tile[(r0 + m) << 6];
        float4 lo0 = *(const float4*)(ar + (((2 * kg)     ^ r7) << 2));
        float4 hi0 = *(const float4*)(ar + (((2 * kg + 1) ^ r7) << 2));
        float4 lo1 = *(const float4*)(ar + (((2 * kg + 8) ^ r7) << 2));
        float4 hi1 = *(const float4*)(ar + (((2 * kg + 9) ^ r7) << 2));
        bf16x8 a0, a1;
        CVT8(a0, lo0, hi0)
        CVT8(a1, lo1, hi1)
        f32x4 acc[4];
#pragma unroll
        for (int t = 0; t < 4; ++t) {
            acc[t] = 0.f;
            const ushort_t* bp = wt1 + ((16 * t + m) << 6) + (kg << 3);
            bf16x8 b0 = *(const bf16x8*)bp;
            bf16x8 b1 = *(const bf16x8*)(bp + 32);
            acc[t] = __builtin_amdgcn_mfma_f32_16x16x32_bf16(a0, b0, acc[t], 0, 0, 0);
            acc[t] = __builtin_amdgcn_mfma_f32_16x16x32_bf16(a1, b1, acc[t], 0, 0, 0);
        }
#pragma unroll
        for (int t = 0; t < 4; ++t) {
            float bv = bs1[16 * t + m];
#pragma unroll
            for (int reg = 0; reg < 4; ++reg) {
                int lr  = r0 + (kg << 2) + reg;           // local row
                int blkc = ((2 * t + (m >> 3)) ^ (lr & 7));
                hl[(lr << 6) + (blkc << 3) + (m & 7)] = f2bf(fmaxf(acc[t][reg] + bv, 0.f));
            }
        }
    }
    __syncthreads();
    // ---- GEMM2 (MFMA): out = h1 @ W2 + b2 [+res]; relu; pool ----
    {
        const ushort_t* hr = &hl[(r0 + m) << 6];
        bf16x8 a0 = *(const bf16x8*)(hr + (((kg)     ^ r7) << 3));
        bf16x8 a1 = *(const bf16x8*)(hr + (((4 + kg) ^ r7) << 3));
        f32x4 acc[4];
#pragma unroll
        for (int t = 0; t < 4; ++t) {
            acc[t] = 0.f;
            const ushort_t* bp = wt2 + ((16 * t + m) << 6) + (kg << 3);
            bf16x8 b0 = *(const bf16x8*)bp;
            bf16x8 b1 = *(const bf16x8*)(bp + 32);
            acc[t] = __builtin_amdgcn_mfma_f32_16x16x32_bf16(a0, b0, acc[t], 0, 0, 0);
            acc[t] = __builtin_amdgcn_mfma_f32_16x16x32_bf16(a1, b1, acc[t], 0, 0, 0);
        }
        float bv2[4];
#pragma unroll
        for (int t = 0; t < 4; ++t) bv2[t] = bs2[16 * t + m];
        int baserow = node0 + r0 + (kg << 2);
        float pool[4] = {0.f, 0.f, 0.f, 0.f};
        int gcur = -1;
#pragma unroll
        for (int reg = 0; reg < 4; ++reg) {
            int node = baserow + reg;
            if (node >= NNODES) break;
            int g = batch[node];
            if (g != gcur) {
                if (gcur >= 0) {
#pragma unroll
                    for (int t = 0; t < 4; ++t) {
                        atomicAdd(&G[gcur * CAT + stage * HID + 16 * t + m], pool[t]);
                        pool[t] = 0.f;
                    }
                }
                gcur = g;
            }
#pragma unroll
            for (int t = 0; t < 4; ++t) {
                int c = 16 * t + m;
                float v = acc[t][reg] + bv2[t];
                if (do_res) {
                    v += XRES[((size_t)node << 6) + c];
                    XRES[((size_t)node << 6) + c] = v;
                }
                float xn = fmaxf(v, 0.f);
                Xb_out[((size_t)node << 6) + c] = f2bf(xn);
                pool[t] += xn;
            }
        }
        if (gcur >= 0) {
#pragma unroll
            for (int t = 0; t < 4; ++t)
                atomicAdd(&G[gcur * CAT + stage * HID + 16 * t + m], pool[t]);
        }
    }
}

// ---------- dense pieces ----------

__global__ void pre_kernel(const float* __restrict__ xin, const int* __restrict__ batch,
                           const float* __restrict__ w, const float* __restrict__ b,
                           ushort_t* __restrict__ Xb, float* __restrict__ XRES,
                           float* __restrict__ G) {
    __shared__ float sw[INDIM * HID];
    for (int i = threadIdx.x; i < INDIM * HID; i += blockDim.x) sw[i] = w[i];
    __syncthreads();
    int lane = threadIdx.x & 63;
    int wid  = blockIdx.x * (blockDim.x >> 6) + (threadIdx.x >> 6);
    int nW   = gridDim.x * (blockDim.x >> 6);
    int chunk = (NNODES + nW - 1) / nW;
    int n0 = wid * chunk, n1 = min(n0 + chunk, NNODES);
    if (n0 >= n1) return;
    float bb   = b[lane];
    float pool = 0.f;
    int   curg = batch[n0];
    for (int node = n0; node < n1; ++node) {
        float in  = (lane < INDIM) ? xin[node * INDIM + lane] : 0.f;
        float acc = bb;
#pragma unroll
        for (int k = 0; k < INDIM; ++k)
            acc = fmaf(bcast(in, k), sw[k * HID + lane], acc);
        Xb[((size_t)node << 6) + lane]   = f2bf(acc);
        XRES[((size_t)node << 6) + lane] = acc;
        int g = batch[node];
        if (g != curg) {
            atomicAdd(&G[curg * CAT + lane], pool);
            pool = 0.f; curg = g;
        }
        pool += acc;
    }
    atomicAdd(&G[curg * CAT + lane], pool);
}

__global__ void post_kernel(const float* __restrict__ GQ, const float* __restrict__ GC,
                            const float* __restrict__ w1, const float* __restrict__ b1,
                            const float* __restrict__ w2, const float* __restrict__ b2,
                            float* __restrict__ out) {
    int g    = blockIdx.x;
    int lane = threadIdx.x;
    __shared__ float h1q[HID], h1c[HID];
    float aq = b1[lane], ac = b1[lane];
    for (int k = 0; k < CAT; ++k) {
        float w = w1[k * HID + lane];
        aq = fmaf(GQ[g * CAT + k], w, aq);
        ac = fmaf(GC[g * CAT + k], w, ac);
    }
    h1q[lane] = fmaxf(aq, 0.f);
    h1c[lane] = fmaxf(ac, 0.f);
    __syncthreads();
    float s = 0.f;
    if (lane < ODIM) {
        float oq = b2[lane], oc = b2[lane];
        for (int k = 0; k < HID; ++k) {
            float w = w2[k * ODIM + lane];
            oq = fmaf(h1q[k], w, oq);
            oc = fmaf(h1c[k], w, oc);
        }
        s = fabsf(oq - oc);
    }
    for (int off = 16; off; off >>= 1) s += __shfl_down(s, off, 64);
    if (lane == 0) out[g] = s;
}

extern "C" void kernel_launch(void* const* d_in, const int* in_sizes, int n_in,
                              void* d_out, int out_size, void* d_ws, size_t ws_size,
                              hipStream_t stream) {
    const float* x_q     = (const float*)d_in[0];
    const int*   ei_q    = (const int*)d_in[1];
    const int*   batch_q = (const int*)d_in[2];
    const float* x_c     = (const float*)d_in[3];
    const int*   ei_c    = (const int*)d_in[4];
    const int*   batch_c = (const int*)d_in[5];
    const float* pre_w   = (const float*)d_in[6];
    const float* pre_b   = (const float*)d_in[7];
    const float* conv_w1 = (const float*)d_in[8];
    const float* conv_b1 = (const float*)d_in[9];
    const float* conv_w2 = (const float*)d_in[10];
    const float* conv_b2 = (const float*)d_in[11];
    const float* post_w1 = (const float*)d_in[12];
    const float* post_b1 = (const float*)d_in[13];
    const float* post_w2 = (const float*)d_in[14];
    const float* post_b2 = (const float*)d_in[15];

    float* ws   = (float*)d_ws;
    float* XRES = ws;                        // N*H fp32
    float* GQ   = XRES + NNODES * HID;       // NG*CAT
    float* GC   = GQ + NG * CAT;             // NG*CAT
    int*   ccounts = (int*)(GC + NG * CAT);  // NCB
    int*   cstart  = ccounts + NCB;          // NCB+1
    int*   ccursor = cstart + NCB + 1;       // NCB
    int*   start   = ccursor + NCB;          // NNODES+1
    unsigned* packed0 = (unsigned*)(start + NNODES + 1);  // NEDGES+64 (padded)
    unsigned* packed  = packed0 + NEDGES + 64;            // NEDGES+64 (padded)
    ushort_t* XbfA = (ushort_t*)(packed + NEDGES + 64);   // N*H bf16
    ushort_t* XbfB = XbfA + (size_t)NNODES * HID;         // N*H bf16
    ushort_t* wtbuf = XbfB + (size_t)NNODES * HID;        // 8*64*64 bf16

    hipMemsetAsync(GQ, 0, 2 * NG * CAT * sizeof(float), stream);
    wtprep_kernel<<<8, 256, 0, stream>>>(conv_w1, conv_w2, wtbuf);

    for (int side = 0; side < 2; ++side) {
        const float* xin   = side ? x_c : x_q;
        const int*   ei    = side ? ei_c : ei_q;
        const int*   batch = side ? batch_c : batch_q;
        float*       G     = side ? GC : GQ;

        hipMemsetAsync(ccounts, 0, NCB * sizeof(int), stream);
        radix1a_kernel<<<256, 256, 0, stream>>>(ei, ccounts);
        cscan_kernel<<<1, 256, 0, stream>>>(ccounts, cstart, ccursor);
        radix1b_kernel<<<NR1, 256, 0, stream>>>(ei, ccursor, packed0);
        radix2_kernel<<<NCB, 256, 0, stream>>>(packed0, cstart, start, packed);

        pre_kernel<<<1024, 256, 0, stream>>>(xin, batch, pre_w, pre_b, XbfA, XRES, G);

        ushort_t* xcur = XbfA;
        ushort_t* xnxt = XbfB;
        for (int l = 0; l < 4; ++l) {
            fused_kernel<<<NB, 256, 0, stream>>>(xcur, xnxt, XRES, G, batch, packed, start,
                                                 wtbuf + l * HID * HID, conv_b1 + l * HID,
                                                 wtbuf + (4 + l) * HID * HID, conv_b2 + l * HID,
                                                 l & 1, l + 1);
            ushort_t* t = xcur; xcur = xnxt; xnxt = t;
        }
    }

    post_kernel<<<NG, 64, 0, stream>>>(GQ, GC, post_w1, post_b1, post_w2, post_b2,
                                       (float*)d_out);
}